// Round 2
// 157.122 us; speedup vs baseline: 1.1289x; 1.1289x over previous
//
#include <hip/hip_runtime.h>
#include <hip/hip_bf16.h>

#define NS 32768          // B*S samples
#define EMB 512
#define KDIM 2048
#define BM 128
#define BN 256
#define NITER (KDIM / 32)

typedef float f32x16 __attribute__((ext_vector_type(16)));
typedef __bf16 bf16x8 __attribute__((ext_vector_type(8)));
typedef __bf16 bf16x2 __attribute__((ext_vector_type(2)));
typedef unsigned int u32;
typedef unsigned int u32x2 __attribute__((ext_vector_type(2)));
typedef const __attribute__((address_space(1))) u32* gptr_t;
typedef __attribute__((address_space(3))) u32* lptr_t;

#if __has_builtin(__builtin_amdgcn_permlane32_swap)
#define HAS_PLS 1
#else
#define HAS_PLS 0
#endif

__device__ __forceinline__ void gload_lds16(const void* g, void* l) {
    __builtin_amdgcn_global_load_lds((gptr_t)g, (lptr_t)l, 16, 0, 0);
}

// pack two relu'd floats into one u32 of 2 bf16 (compiler emits v_cvt_pk_bf16_f32)
__device__ __forceinline__ u32 pkrelu(float lo, float hi) {
    union { bf16x2 h; u32 u; } c;
    c.h[0] = (__bf16)fmaxf(lo, 0.f);
    c.h[1] = (__bf16)fmaxf(hi, 0.f);
    return c.u;
}

__device__ __forceinline__ bf16x8 mk_af(u32 a, u32 b, u32 c, u32 d) {
    union { u32 u[4]; bf16x8 v; } t;
    t.u[0] = a; t.u[1] = b; t.u[2] = c; t.u[3] = d;
    return t.v;
}

// ---- prep: W2 -> bf16 (1024 blocks); W1 -> bf16 (16 blocks) ----
__global__ __launch_bounds__(256) void k_prep(const float* __restrict__ W2,
                                              const float* __restrict__ W1,
                                              __hip_bfloat16* __restrict__ W2b,
                                              __hip_bfloat16* __restrict__ W1bg) {
    int t = threadIdx.x;
    if (blockIdx.x < 1024) {
        int i = (blockIdx.x * 256 + t) * 4;
        float4 v = *(const float4*)(W2 + i);
        __hip_bfloat16 o[4];
        o[0] = __float2bfloat16(v.x); o[1] = __float2bfloat16(v.y);
        o[2] = __float2bfloat16(v.z); o[3] = __float2bfloat16(v.w);
        *(ulong1*)(W2b + i) = *(ulong1*)o;
    } else {
        int j = (blockIdx.x - 1024) * 1024 + t * 4;   // 16 blocks x 1024
        float4 w = *(const float4*)(W1 + j);
        __hip_bfloat16 p[4];
        p[0] = __float2bfloat16(w.x); p[1] = __float2bfloat16(w.y);
        p[2] = __float2bfloat16(w.z); p[3] = __float2bfloat16(w.w);
        *(ulong1*)(W1bg + j) = *(ulong1*)p;
    }
}

// ---- fused: C[128,256-tile] = relu(ev @ W1^T + b1) @ W2b^T + b2 ----
// GEMM1 on the MFMA pipe: per 32-wide K-chunk,
//   H' = mfma_32x32x16( A = W1[k0+l31][0..8] (K-padded w/ zeros), B = ev )
// puts H[hidden-chunk][sample = l31] in each lane's C/D regs (bias as C-in).
// relu + cvt_pk + 4x permlane32_swap rearrange into the exact A-fragment
// layout (A[row=l31][k = half*8 + j]) the GEMM2 MFMA consumes.
// v_permlane32_swap_b32 dst,src semantics: DST[63:32] <-> SRC[31:0].
// So pls(w0, wA) gives: w0 = {half0: own pk(h0,h1), half1: half0 pk(h8,h9)},
//                       wA = {half0: half1 pk(h4,h5), half1: own pk(h12,h13)}
// i.e. A-frag positions 0 and 2 correct for BOTH halves.
// B (W2) staging is double-buffered: stage issued at iter top, drained by the
// single end-of-iter __syncthreads -> full compute phase of latency hiding.
__global__ __launch_bounds__(256, 2) void k_gemm(
        const float* __restrict__ x,       // [NS, 8]
        const float* __restrict__ params,  // [8, 3]
        const __hip_bfloat16* __restrict__ W1bg,  // [2048, 8] bf16
        const float* __restrict__ b1,      // [2048]
        const __hip_bfloat16* __restrict__ W2b,   // [512, 2048] bf16
        const float* __restrict__ b2,      // [512]
        float* __restrict__ C) {           // [NS, 512]
    __shared__ __hip_bfloat16 Bs[2][16 * 512]; // double-buffered, 2 x 16 KB
    __shared__ __hip_bfloat16 W1s[KDIM * 8];   // 32 KB
    __shared__ float b1s[KDIM];                // 8 KB
    __shared__ __hip_bfloat16 evs[BM * 8];     // 2 KB   -> total 75776 B, 2 blk/CU

    int tid = threadIdx.x, wave = tid >> 6, lane = tid & 63;
    int l31 = lane & 31, half = lane >> 5;
    int bx = blockIdx.x, bm = bx >> 1, bn = bx & 1;

    // --- inline ev for this block's 128 rows (threads 0..127, 1 sample each)
    if (tid < 128) {
        float K1[8], K2[8];
        #pragma unroll
        for (int i = 0; i < 8; i++) {
            float a = params[i*3+0], b = params[i*3+1], g = params[i*3+2];
            float sa, ca, sb, cb, sg, cg;
            __sincosf(a, &sa, &ca);
            __sincosf(b, &sb, &cb);
            __sincosf(g, &sg, &cg);
            K1[i] = sa*sb*sg + ca*cg;
            K2[i] = cb*sg;
        }
        int n = bm * BM + tid;
        float4 x0 = *(const float4*)(x + (size_t)n*8);
        float4 x1 = *(const float4*)(x + (size_t)n*8 + 4);
        float xs[8] = {x0.x, x0.y, x0.z, x0.w, x1.x, x1.y, x1.z, x1.w};
        float z[8];
        #pragma unroll
        for (int i = 0; i < 8; i++) {
            float s, c;
            __sincosf(xs[i], &s, &c);
            z[i] = c * K1[i] - s * K2[i];
        }
        float evv[8];
        float p = z[0];
        #pragma unroll
        for (int j = 1; j < 8; j++) { p *= z[j]; evv[j] = p; }
        float sfx = z[7];
        #pragma unroll
        for (int j = 6; j >= 1; j--) sfx *= z[j];
        evv[0] = sfx;
        __hip_bfloat16 o[8];
        #pragma unroll
        for (int i = 0; i < 8; i++) o[i] = __float2bfloat16(evv[i]);
        *(bf16x8*)&evs[tid * 8] = *(bf16x8*)o;
    }
    // --- stage W1 (bf16) + b1 (f32) into LDS
    for (int i = tid; i < KDIM; i += 256) {
        *(bf16x8*)&W1s[i * 8] = *(const bf16x8*)(W1bg + (size_t)i * 8);
        b1s[i] = b1[i];
    }

    // B staging pointers: wave stages frags f = wave*4 .. wave*4+3
    const __hip_bfloat16* gBp[4];
    #pragma unroll
    for (int i = 0; i < 4; i++) {
        int f = wave * 4 + i, ni = f >> 1, t = f & 1;
        gBp[i] = W2b + (size_t)(bn*BN + ni*32 + l31) * KDIM + t*16 + half*8;
    }
    // prologue: stage buffer 0 (k0 = 0)
    #pragma unroll
    for (int i = 0; i < 4; i++) {
        gload_lds16(gBp[i], &Bs[0][(wave*4 + i) * 512]);
        gBp[i] += 32;
    }

    __syncthreads();   // evs/W1s/b1s written, Bs[0] staged+drained

    // loop-invariant MFMA1 B-operand: this lane's ev row (garbage upper-K half
    // is multiplied by the zeroed upper-K half of the W1 A-fragment -> exact 0)
    bf16x8 evB = *(bf16x8*)&evs[(wave * 32 + l31) * 8];

    f32x16 acc[8] = {};

    for (int it = 0; it < NITER; ++it) {
        const int k0 = it * 32;
        const int cb = it & 1;

        // issue next-tile staging first: drained only at end-of-iter barrier
        if (it + 1 < NITER) {
            #pragma unroll
            for (int i = 0; i < 4; i++) {
                gload_lds16(gBp[i], &Bs[cb ^ 1][(wave*4 + i) * 512]);
                gBp[i] += 32;
            }
        }

        // ---- GEMM1 chunk on the MFMA pipe ----
        // A-frag: lane holds W1[k0+l31][half*8 + j]; zero upper-K half
        bf16x8 w1f = {};
        if (half == 0) w1f = *(const bf16x8*)&W1s[(k0 + l31) * 8];
        // bias as C-in, laid out per C/D mapping row=(r&3)+8*(r>>2)+4*half
        float4 c0 = *(const float4*)&b1s[k0 + 4*half];
        float4 c1 = *(const float4*)&b1s[k0 + 8 + 4*half];
        float4 c2 = *(const float4*)&b1s[k0 + 16 + 4*half];
        float4 c3 = *(const float4*)&b1s[k0 + 24 + 4*half];
        f32x16 h;
        h[0] = c0.x; h[1] = c0.y; h[2]  = c0.z; h[3]  = c0.w;
        h[4] = c1.x; h[5] = c1.y; h[6]  = c1.z; h[7]  = c1.w;
        h[8] = c2.x; h[9] = c2.y; h[10] = c2.z; h[11] = c2.w;
        h[12] = c3.x; h[13] = c3.y; h[14] = c3.z; h[15] = c3.w;
        h = __builtin_amdgcn_mfma_f32_32x32x16_bf16(w1f, evB, h, 0, 0, 0);

        // relu + pack to bf16 pairs; lane holds hidden offsets
        //   half0: {0-3,8-11,16-19,24-27}, half1: {4-7,12-15,20-23,28-31}
        u32 w0  = pkrelu(h[0],  h[1]);  u32 w1v = pkrelu(h[2],  h[3]);
        u32 wA  = pkrelu(h[4],  h[5]);  u32 wB  = pkrelu(h[6],  h[7]);
        u32 w2v = pkrelu(h[8],  h[9]);  u32 w3v = pkrelu(h[10], h[11]);
        u32 wC  = pkrelu(h[12], h[13]); u32 wD  = pkrelu(h[14], h[15]);
        // cross-half exchange -> A-frag layout A[row=l31][k = half*8 + j]
        // pls(dst,src): DST[63:32] <-> SRC[31:0]
#if HAS_PLS
        { u32x2 r = __builtin_amdgcn_permlane32_swap(w0,  wA, false, false); w0  = r[0]; wA = r[1]; }
        { u32x2 r = __builtin_amdgcn_permlane32_swap(w1v, wB, false, false); w1v = r[0]; wB = r[1]; }
        { u32x2 r = __builtin_amdgcn_permlane32_swap(w2v, wC, false, false); w2v = r[0]; wC = r[1]; }
        { u32x2 r = __builtin_amdgcn_permlane32_swap(w3v, wD, false, false); w3v = r[0]; wD = r[1]; }
        bf16x8 af0 = mk_af(w0, w1v, wA, wB);     // k2 = k0      + half*8 + 0..7
        bf16x8 af1 = mk_af(w2v, w3v, wC, wD);    // k2 = k0 + 16 + half*8 + 0..7
#else
        int pl = lane ^ 32;
        u32 pw0 = __shfl((int)w0,  pl), pw1 = __shfl((int)w1v, pl);
        u32 pwA = __shfl((int)wA,  pl), pwB = __shfl((int)wB,  pl);
        u32 pw2 = __shfl((int)w2v, pl), pw3 = __shfl((int)w3v, pl);
        u32 pwC = __shfl((int)wC,  pl), pwD = __shfl((int)wD,  pl);
        bf16x8 af0 = half ? mk_af(pwA, pwB, wA, wB) : mk_af(w0,  w1v, pw0, pw1);
        bf16x8 af1 = half ? mk_af(pwC, pwD, wC, wD) : mk_af(w2v, w3v, pw2, pw3);
#endif

        // ---- GEMM2: 16 MFMAs on the staged B tile ----
        #pragma unroll
        for (int ni = 0; ni < 8; ni++) {
            bf16x8 bfr = *(bf16x8*)&Bs[cb][(ni*2 + 0) * 512 + lane * 8];
            acc[ni] = __builtin_amdgcn_mfma_f32_32x32x16_bf16(af0, bfr, acc[ni], 0, 0, 0);
        }
        #pragma unroll
        for (int ni = 0; ni < 8; ni++) {
            bf16x8 bfr = *(bf16x8*)&Bs[cb][(ni*2 + 1) * 512 + lane * 8];
            acc[ni] = __builtin_amdgcn_mfma_f32_32x32x16_bf16(af1, bfr, acc[ni], 0, 0, 0);
        }

        __syncthreads();  // drains next-stage vmcnt AFTER compute; flips buffer
    }

    // epilogue: 32x32 C/D layout: col = lane&31, row = (r&3)+8*(r>>2)+4*half
    int rbase = bm*BM + wave*32 + 4*half;
    #pragma unroll
    for (int ni = 0; ni < 8; ni++) {
        int col = bn*BN + ni*32 + l31;
        float bias = b2[col];
        #pragma unroll
        for (int r = 0; r < 16; r++) {
            int row = rbase + (r & 3) + 8 * (r >> 2);
            C[(size_t)row * EMB + col] = acc[ni][r] + bias;
        }
    }
}

extern "C" void kernel_launch(void* const* d_in, const int* in_sizes, int n_in,
                              void* d_out, int out_size, void* d_ws, size_t ws_size,
                              hipStream_t stream) {
    const float* x      = (const float*)d_in[0];  // [16,2048,8]
    const float* params = (const float*)d_in[1];  // [8,3]
    const float* W1     = (const float*)d_in[2];  // [2048,8]
    const float* b1     = (const float*)d_in[3];  // [2048]
    const float* W2     = (const float*)d_in[4];  // [512,2048]
    const float* b2     = (const float*)d_in[5];  // [512]
    float* out = (float*)d_out;                   // [32768,512]

    char* ws = (char*)d_ws;
    __hip_bfloat16* W2b  = (__hip_bfloat16*)ws;              // 2 MB
    __hip_bfloat16* W1bg = (__hip_bfloat16*)(ws + 2097152);  // 32 KB

    k_prep<<<1040, 256, 0, stream>>>(W2, W1, W2b, W1bg);
    k_gemm<<<(NS/BM) * (EMB/BN), 256, 0, stream>>>(x, params, W1bg, b1, W2b, b2, out);
}

// Round 3
// 151.843 us; speedup vs baseline: 1.1682x; 1.0348x over previous
//
#include <hip/hip_runtime.h>
#include <hip/hip_bf16.h>

#define NS 32768          // B*S samples
#define EMB 512
#define KDIM 2048
#define BM 256
#define BN 128
#define NITER (KDIM / 32)

typedef float f32x16 __attribute__((ext_vector_type(16)));
typedef __bf16 bf16x8 __attribute__((ext_vector_type(8)));
typedef __bf16 bf16x2 __attribute__((ext_vector_type(2)));
typedef unsigned int u32;
typedef unsigned int u32x2 __attribute__((ext_vector_type(2)));
typedef const __attribute__((address_space(1))) u32* gptr_t;
typedef __attribute__((address_space(3))) u32* lptr_t;

#if __has_builtin(__builtin_amdgcn_permlane32_swap)
#define HAS_PLS 1
#else
#define HAS_PLS 0
#endif

__device__ __forceinline__ void gload_lds16(const void* g, void* l) {
    __builtin_amdgcn_global_load_lds((gptr_t)g, (lptr_t)l, 16, 0, 0);
}

// pack two relu'd floats into one u32 of 2 bf16 (compiler emits v_cvt_pk_bf16_f32)
__device__ __forceinline__ u32 pkrelu(float lo, float hi) {
    union { bf16x2 h; u32 u; } c;
    c.h[0] = (__bf16)fmaxf(lo, 0.f);
    c.h[1] = (__bf16)fmaxf(hi, 0.f);
    return c.u;
}

__device__ __forceinline__ bf16x8 mk_af(u32 a, u32 b, u32 c, u32 d) {
    union { u32 u[4]; bf16x8 v; } t;
    t.u[0] = a; t.u[1] = b; t.u[2] = c; t.u[3] = d;
    return t.v;
}

// relu+pack GEMM1 C/D regs -> two GEMM2 A-fragments (verified in round 2).
// pls(dst,src): DST[63:32] <-> SRC[31:0].
__device__ __forceinline__ void h_to_af(const f32x16 h, int lane, int half,
                                        bf16x8& af0, bf16x8& af1) {
    u32 w0  = pkrelu(h[0],  h[1]);  u32 w1v = pkrelu(h[2],  h[3]);
    u32 wA  = pkrelu(h[4],  h[5]);  u32 wB  = pkrelu(h[6],  h[7]);
    u32 w2v = pkrelu(h[8],  h[9]);  u32 w3v = pkrelu(h[10], h[11]);
    u32 wC  = pkrelu(h[12], h[13]); u32 wD  = pkrelu(h[14], h[15]);
#if HAS_PLS
    { u32x2 r = __builtin_amdgcn_permlane32_swap(w0,  wA, false, false); w0  = r[0]; wA = r[1]; }
    { u32x2 r = __builtin_amdgcn_permlane32_swap(w1v, wB, false, false); w1v = r[0]; wB = r[1]; }
    { u32x2 r = __builtin_amdgcn_permlane32_swap(w2v, wC, false, false); w2v = r[0]; wC = r[1]; }
    { u32x2 r = __builtin_amdgcn_permlane32_swap(w3v, wD, false, false); w3v = r[0]; wD = r[1]; }
    af0 = mk_af(w0, w1v, wA, wB);     // k2 = k0      + half*8 + 0..7
    af1 = mk_af(w2v, w3v, wC, wD);    // k2 = k0 + 16 + half*8 + 0..7
#else
    int pl = lane ^ 32;
    u32 pw0 = __shfl((int)w0,  pl), pw1 = __shfl((int)w1v, pl);
    u32 pwA = __shfl((int)wA,  pl), pwB = __shfl((int)wB,  pl);
    u32 pw2 = __shfl((int)w2v, pl), pw3 = __shfl((int)w3v, pl);
    u32 pwC = __shfl((int)wC,  pl), pwD = __shfl((int)wD,  pl);
    af0 = half ? mk_af(pwA, pwB, wA, wB) : mk_af(w0,  w1v, pw0, pw1);
    af1 = half ? mk_af(pwC, pwD, wC, wD) : mk_af(w2v, w3v, pw2, pw3);
#endif
}

// ---- prep: W2 -> bf16 (1024 blocks); W1 -> bf16 (16 blocks) ----
__global__ __launch_bounds__(256) void k_prep(const float* __restrict__ W2,
                                              const float* __restrict__ W1,
                                              __hip_bfloat16* __restrict__ W2b,
                                              __hip_bfloat16* __restrict__ W1bg) {
    int t = threadIdx.x;
    if (blockIdx.x < 1024) {
        int i = (blockIdx.x * 256 + t) * 4;
        float4 v = *(const float4*)(W2 + i);
        __hip_bfloat16 o[4];
        o[0] = __float2bfloat16(v.x); o[1] = __float2bfloat16(v.y);
        o[2] = __float2bfloat16(v.z); o[3] = __float2bfloat16(v.w);
        *(ulong1*)(W2b + i) = *(ulong1*)o;
    } else {
        int j = (blockIdx.x - 1024) * 1024 + t * 4;   // 16 blocks x 1024
        float4 w = *(const float4*)(W1 + j);
        __hip_bfloat16 p[4];
        p[0] = __float2bfloat16(w.x); p[1] = __float2bfloat16(w.y);
        p[2] = __float2bfloat16(w.z); p[3] = __float2bfloat16(w.w);
        *(ulong1*)(W1bg + j) = *(ulong1*)p;
    }
}

// ---- fused: C[256,128-tile] = relu(ev @ W1^T + b1) @ W2b^T + b2 ----
// Retiled vs round 2: BM=256 x BN=128, each wave owns TWO 32-row groups.
// Every W2 B-fragment ds_read_b128 now feeds TWO MFMAs (one per row group)
// -> LDS B traffic halves. W1 A-frag + bias C-in are shared across groups.
// GEMM1 on the MFMA pipe (zero-padded K), relu+cvt_pk+permlane32_swap
// produce GEMM2 A-fragments in-register (layout verified round 2).
// B staging double-buffered, single end-of-iter barrier.
__global__ __launch_bounds__(256, 2) void k_gemm(
        const float* __restrict__ x,       // [NS, 8]
        const float* __restrict__ params,  // [8, 3]
        const __hip_bfloat16* __restrict__ W1bg,  // [2048, 8] bf16
        const float* __restrict__ b1,      // [2048]
        const __hip_bfloat16* __restrict__ W2b,   // [512, 2048] bf16
        const float* __restrict__ b2,      // [512]
        float* __restrict__ C) {           // [NS, 512]
    __shared__ __hip_bfloat16 Bs[2][8 * 512];  // double-buffered, 2 x 8 KB
    __shared__ __hip_bfloat16 W1s[KDIM * 8];   // 32 KB
    __shared__ float b1s[KDIM];                // 8 KB
    __shared__ __hip_bfloat16 evs[BM * 8];     // 4 KB   -> total 60 KB, 2 blk/CU

    int tid = threadIdx.x, wave = tid >> 6, lane = tid & 63;
    int l31 = lane & 31, half = lane >> 5;
    int bx = blockIdx.x, bm = bx >> 2, bn = bx & 3;

    // --- inline ev for this block's 256 rows (1 sample per thread)
    {
        float K1[8], K2[8];
        #pragma unroll
        for (int i = 0; i < 8; i++) {
            float a = params[i*3+0], b = params[i*3+1], g = params[i*3+2];
            float sa, ca, sb, cb, sg, cg;
            __sincosf(a, &sa, &ca);
            __sincosf(b, &sb, &cb);
            __sincosf(g, &sg, &cg);
            K1[i] = sa*sb*sg + ca*cg;
            K2[i] = cb*sg;
        }
        int n = bm * BM + tid;
        float4 x0 = *(const float4*)(x + (size_t)n*8);
        float4 x1 = *(const float4*)(x + (size_t)n*8 + 4);
        float xs[8] = {x0.x, x0.y, x0.z, x0.w, x1.x, x1.y, x1.z, x1.w};
        float z[8];
        #pragma unroll
        for (int i = 0; i < 8; i++) {
            float s, c;
            __sincosf(xs[i], &s, &c);
            z[i] = c * K1[i] - s * K2[i];
        }
        float evv[8];
        float p = z[0];
        #pragma unroll
        for (int j = 1; j < 8; j++) { p *= z[j]; evv[j] = p; }
        float sfx = z[7];
        #pragma unroll
        for (int j = 6; j >= 1; j--) sfx *= z[j];
        evv[0] = sfx;
        __hip_bfloat16 o[8];
        #pragma unroll
        for (int i = 0; i < 8; i++) o[i] = __float2bfloat16(evv[i]);
        *(bf16x8*)&evs[tid * 8] = *(bf16x8*)o;
    }
    // --- stage W1 (bf16) + b1 (f32) into LDS
    for (int i = tid; i < KDIM; i += 256) {
        *(bf16x8*)&W1s[i * 8] = *(const bf16x8*)(W1bg + (size_t)i * 8);
        b1s[i] = b1[i];
    }

    // B staging: wave stages frags f = wave*2, wave*2+1  (8 frags = 4 ni x 2 t)
    const __hip_bfloat16* gBp[2];
    #pragma unroll
    for (int i = 0; i < 2; i++) {
        int f = wave * 2 + i, ni = f >> 1, t = f & 1;
        gBp[i] = W2b + (size_t)(bn*BN + ni*32 + l31) * KDIM + t*16 + half*8;
    }
    // prologue: stage buffer 0 (k0 = 0)
    #pragma unroll
    for (int i = 0; i < 2; i++) {
        gload_lds16(gBp[i], &Bs[0][(wave*2 + i) * 512]);
        gBp[i] += 32;
    }

    __syncthreads();   // evs/W1s/b1s written, Bs[0] staged+drained

    // loop-invariant GEMM1 B-operands: the wave's two 32-sample groups
    bf16x8 evB0 = *(bf16x8*)&evs[(wave * 64 +      l31) * 8];
    bf16x8 evB1 = *(bf16x8*)&evs[(wave * 64 + 32 + l31) * 8];

    f32x16 acc[8] = {};   // [rg*4 + ni]

    for (int it = 0; it < NITER; ++it) {
        const int k0 = it * 32;
        const int cb = it & 1;

        // issue next-tile staging first: drained only at end-of-iter barrier
        if (it + 1 < NITER) {
            #pragma unroll
            for (int i = 0; i < 2; i++) {
                gload_lds16(gBp[i], &Bs[cb ^ 1][(wave*2 + i) * 512]);
                gBp[i] += 32;
            }
        }

        // ---- GEMM1 chunk (shared A/bias across both row groups) ----
        bf16x8 w1f = {};
        if (half == 0) w1f = *(const bf16x8*)&W1s[(k0 + l31) * 8];
        float4 c0 = *(const float4*)&b1s[k0 + 4*half];
        float4 c1 = *(const float4*)&b1s[k0 + 8 + 4*half];
        float4 c2 = *(const float4*)&b1s[k0 + 16 + 4*half];
        float4 c3 = *(const float4*)&b1s[k0 + 24 + 4*half];
        f32x16 hb;
        hb[0] = c0.x; hb[1] = c0.y; hb[2]  = c0.z; hb[3]  = c0.w;
        hb[4] = c1.x; hb[5] = c1.y; hb[6]  = c1.z; hb[7]  = c1.w;
        hb[8] = c2.x; hb[9] = c2.y; hb[10] = c2.z; hb[11] = c2.w;
        hb[12] = c3.x; hb[13] = c3.y; hb[14] = c3.z; hb[15] = c3.w;

        f32x16 h0 = __builtin_amdgcn_mfma_f32_32x32x16_bf16(w1f, evB0, hb, 0, 0, 0);
        bf16x8 af00, af01;
        h_to_af(h0, lane, half, af00, af01);
        f32x16 h1 = __builtin_amdgcn_mfma_f32_32x32x16_bf16(w1f, evB1, hb, 0, 0, 0);
        bf16x8 af10, af11;
        h_to_af(h1, lane, half, af10, af11);

        // ---- GEMM2: 8 B-frag reads, 16 MFMAs (each frag feeds both groups)
        #pragma unroll
        for (int ni = 0; ni < 4; ni++) {
            bf16x8 bfr = *(bf16x8*)&Bs[cb][(ni*2 + 0) * 512 + lane * 8];
            acc[ni]     = __builtin_amdgcn_mfma_f32_32x32x16_bf16(af00, bfr, acc[ni],     0, 0, 0);
            acc[4 + ni] = __builtin_amdgcn_mfma_f32_32x32x16_bf16(af10, bfr, acc[4 + ni], 0, 0, 0);
        }
        #pragma unroll
        for (int ni = 0; ni < 4; ni++) {
            bf16x8 bfr = *(bf16x8*)&Bs[cb][(ni*2 + 1) * 512 + lane * 8];
            acc[ni]     = __builtin_amdgcn_mfma_f32_32x32x16_bf16(af01, bfr, acc[ni],     0, 0, 0);
            acc[4 + ni] = __builtin_amdgcn_mfma_f32_32x32x16_bf16(af11, bfr, acc[4 + ni], 0, 0, 0);
        }

        __syncthreads();  // drains next-stage vmcnt AFTER compute; flips buffer
    }

    // epilogue: 32x32 C/D layout: col = lane&31, row = (r&3)+8*(r>>2)+4*half
    #pragma unroll
    for (int rg = 0; rg < 2; rg++) {
        int rbase = bm*BM + wave*64 + rg*32 + 4*half;
        #pragma unroll
        for (int ni = 0; ni < 4; ni++) {
            int col = bn*BN + ni*32 + l31;
            float bias = b2[col];
            #pragma unroll
            for (int r = 0; r < 16; r++) {
                int row = rbase + (r & 3) + 8 * (r >> 2);
                C[(size_t)row * EMB + col] = acc[rg*4 + ni][r] + bias;
            }
        }
    }
}

extern "C" void kernel_launch(void* const* d_in, const int* in_sizes, int n_in,
                              void* d_out, int out_size, void* d_ws, size_t ws_size,
                              hipStream_t stream) {
    const float* x      = (const float*)d_in[0];  // [16,2048,8]
    const float* params = (const float*)d_in[1];  // [8,3]
    const float* W1     = (const float*)d_in[2];  // [2048,8]
    const float* b1     = (const float*)d_in[3];  // [2048]
    const float* W2     = (const float*)d_in[4];  // [512,2048]
    const float* b2     = (const float*)d_in[5];  // [512]
    float* out = (float*)d_out;                   // [32768,512]

    char* ws = (char*)d_ws;
    __hip_bfloat16* W2b  = (__hip_bfloat16*)ws;              // 2 MB
    __hip_bfloat16* W1bg = (__hip_bfloat16*)(ws + 2097152);  // 32 KB

    k_prep<<<1040, 256, 0, stream>>>(W2, W1, W2b, W1bg);
    k_gemm<<<(NS/BM) * (EMB/BN), 256, 0, stream>>>(x, params, W1bg, b1, W2b, b2, out);
}

// Round 4
// 150.987 us; speedup vs baseline: 1.1748x; 1.0057x over previous
//
#include <hip/hip_runtime.h>
#include <hip/hip_bf16.h>

#define NS 32768          // B*S samples
#define EMB 512
#define KDIM 2048
#define BM 256
#define BN 128
#define NITER (KDIM / 32)

typedef float f32x16 __attribute__((ext_vector_type(16)));
typedef __bf16 bf16x8 __attribute__((ext_vector_type(8)));
typedef __bf16 bf16x2 __attribute__((ext_vector_type(2)));
typedef unsigned int u32;
typedef unsigned int u32x2 __attribute__((ext_vector_type(2)));
typedef const __attribute__((address_space(1))) u32* gptr_t;
typedef __attribute__((address_space(3))) u32* lptr_t;

#if __has_builtin(__builtin_amdgcn_permlane32_swap)
#define HAS_PLS 1
#else
#define HAS_PLS 0
#endif

__device__ __forceinline__ void gload_lds16(const void* g, void* l) {
    __builtin_amdgcn_global_load_lds((gptr_t)g, (lptr_t)l, 16, 0, 0);
}

// pack two relu'd floats into one u32 of 2 bf16 (v_cvt_pk_bf16_f32)
__device__ __forceinline__ u32 pkrelu(float lo, float hi) {
    union { bf16x2 h; u32 u; } c;
    c.h[0] = (__bf16)fmaxf(lo, 0.f);
    c.h[1] = (__bf16)fmaxf(hi, 0.f);
    return c.u;
}

__device__ __forceinline__ bf16x8 mk_af(u32 a, u32 b, u32 c, u32 d) {
    union { u32 u[4]; bf16x8 v; } t;
    t.u[0] = a; t.u[1] = b; t.u[2] = c; t.u[3] = d;
    return t.v;
}

// relu+pack GEMM1 C/D regs -> two GEMM2 A-fragments (verified rounds 2-3).
// pls(dst,src): DST[63:32] <-> SRC[31:0].
__device__ __forceinline__ void h_to_af(const f32x16 h, int lane, int half,
                                        bf16x8& af0, bf16x8& af1) {
    u32 w0  = pkrelu(h[0],  h[1]);  u32 w1v = pkrelu(h[2],  h[3]);
    u32 wA  = pkrelu(h[4],  h[5]);  u32 wB  = pkrelu(h[6],  h[7]);
    u32 w2v = pkrelu(h[8],  h[9]);  u32 w3v = pkrelu(h[10], h[11]);
    u32 wC  = pkrelu(h[12], h[13]); u32 wD  = pkrelu(h[14], h[15]);
#if HAS_PLS
    { u32x2 r = __builtin_amdgcn_permlane32_swap(w0,  wA, false, false); w0  = r[0]; wA = r[1]; }
    { u32x2 r = __builtin_amdgcn_permlane32_swap(w1v, wB, false, false); w1v = r[0]; wB = r[1]; }
    { u32x2 r = __builtin_amdgcn_permlane32_swap(w2v, wC, false, false); w2v = r[0]; wC = r[1]; }
    { u32x2 r = __builtin_amdgcn_permlane32_swap(w3v, wD, false, false); w3v = r[0]; wD = r[1]; }
    af0 = mk_af(w0, w1v, wA, wB);     // k2 = k0      + half*8 + 0..7
    af1 = mk_af(w2v, w3v, wC, wD);    // k2 = k0 + 16 + half*8 + 0..7
#else
    int pl = lane ^ 32;
    u32 pw0 = __shfl((int)w0,  pl), pw1 = __shfl((int)w1v, pl);
    u32 pwA = __shfl((int)wA,  pl), pwB = __shfl((int)wB,  pl);
    u32 pw2 = __shfl((int)w2v, pl), pw3 = __shfl((int)w3v, pl);
    u32 pwC = __shfl((int)wC,  pl), pwD = __shfl((int)wD,  pl);
    af0 = half ? mk_af(pwA, pwB, wA, wB) : mk_af(w0,  w1v, pw0, pw1);
    af1 = half ? mk_af(pwC, pwD, wC, wD) : mk_af(w2v, w3v, pw2, pw3);
#endif
}

// ---- prep: W2 -> bf16 (1024 blocks); W1 -> bf16 (16 blocks) ----
__global__ __launch_bounds__(256) void k_prep(const float* __restrict__ W2,
                                              const float* __restrict__ W1,
                                              __hip_bfloat16* __restrict__ W2b,
                                              __hip_bfloat16* __restrict__ W1bg) {
    int t = threadIdx.x;
    if (blockIdx.x < 1024) {
        int i = (blockIdx.x * 256 + t) * 4;
        float4 v = *(const float4*)(W2 + i);
        __hip_bfloat16 o[4];
        o[0] = __float2bfloat16(v.x); o[1] = __float2bfloat16(v.y);
        o[2] = __float2bfloat16(v.z); o[3] = __float2bfloat16(v.w);
        *(ulong1*)(W2b + i) = *(ulong1*)o;
    } else {
        int j = (blockIdx.x - 1024) * 1024 + t * 4;   // 16 blocks x 1024
        float4 w = *(const float4*)(W1 + j);
        __hip_bfloat16 p[4];
        p[0] = __float2bfloat16(w.x); p[1] = __float2bfloat16(w.y);
        p[2] = __float2bfloat16(w.z); p[3] = __float2bfloat16(w.w);
        *(ulong1*)(W1bg + j) = *(ulong1*)p;
    }
}

// ---- fused: C[256,128-tile] = relu(ev @ W1^T + b1) @ W2b^T + b2 ----
// vs round 3:
//  * b1 folded into the GEMM1 MFMA via the unused k=8 slot:
//    half1 lanes' A-frag = {b1_bf16[row],0..}, half1 lanes' B = {1,0..}
//    -> H = sum_k W1[row,k]*ev[col,k] + b1[row].  C-in = loop-invariant zero.
//    Removes per-iter hb build + b1s float4 reads; b1s(8KB) -> b1h(4KB).
//  * GEMM1+pack software-pipelined one iteration ahead (ping-pong af sets,
//    2x-unrolled loop): next iter's pack VALU overlaps this iter's MFMA2s.
//  * s_setprio(1) around each MFMA2 cluster.
__global__ __launch_bounds__(256, 2) void k_gemm(
        const float* __restrict__ x,       // [NS, 8]
        const float* __restrict__ params,  // [8, 3]
        const __hip_bfloat16* __restrict__ W1bg,  // [2048, 8] bf16
        const float* __restrict__ b1,      // [2048]
        const __hip_bfloat16* __restrict__ W2b,   // [512, 2048] bf16
        const float* __restrict__ b2,      // [512]
        float* __restrict__ C) {           // [NS, 512]
    __shared__ __hip_bfloat16 Bs[2][8 * 512];  // double-buffered, 2 x 8 KB
    __shared__ __hip_bfloat16 W1s[KDIM * 8];   // 32 KB
    __shared__ __hip_bfloat16 b1h[KDIM];       // 4 KB
    __shared__ __hip_bfloat16 evs[BM * 8];     // 4 KB  -> total 56 KB

    int tid = threadIdx.x, wave = tid >> 6, lane = tid & 63;
    int l31 = lane & 31, half = lane >> 5;
    int bx = blockIdx.x, bm = bx >> 2, bn = bx & 3;

    // --- inline ev for this block's 256 rows (1 sample per thread)
    {
        float K1[8], K2[8];
        #pragma unroll
        for (int i = 0; i < 8; i++) {
            float a = params[i*3+0], b = params[i*3+1], g = params[i*3+2];
            float sa, ca, sb, cb, sg, cg;
            __sincosf(a, &sa, &ca);
            __sincosf(b, &sb, &cb);
            __sincosf(g, &sg, &cg);
            K1[i] = sa*sb*sg + ca*cg;
            K2[i] = cb*sg;
        }
        int n = bm * BM + tid;
        float4 x0 = *(const float4*)(x + (size_t)n*8);
        float4 x1 = *(const float4*)(x + (size_t)n*8 + 4);
        float xs[8] = {x0.x, x0.y, x0.z, x0.w, x1.x, x1.y, x1.z, x1.w};
        float z[8];
        #pragma unroll
        for (int i = 0; i < 8; i++) {
            float s, c;
            __sincosf(xs[i], &s, &c);
            z[i] = c * K1[i] - s * K2[i];
        }
        float evv[8];
        float p = z[0];
        #pragma unroll
        for (int j = 1; j < 8; j++) { p *= z[j]; evv[j] = p; }
        float sfx = z[7];
        #pragma unroll
        for (int j = 6; j >= 1; j--) sfx *= z[j];
        evv[0] = sfx;
        __hip_bfloat16 o[8];
        #pragma unroll
        for (int i = 0; i < 8; i++) o[i] = __float2bfloat16(evv[i]);
        *(bf16x8*)&evs[tid * 8] = *(bf16x8*)o;
    }
    // --- stage W1 (bf16) + b1 (bf16) into LDS
    for (int i = tid; i < KDIM; i += 256) {
        *(bf16x8*)&W1s[i * 8] = *(const bf16x8*)(W1bg + (size_t)i * 8);
        b1h[i] = __float2bfloat16(b1[i]);
    }

    // B staging: wave stages frags f = wave*2, wave*2+1  (8 frags = 4 ni x 2 t)
    const __hip_bfloat16* gBp[2];
    #pragma unroll
    for (int i = 0; i < 2; i++) {
        int f = wave * 2 + i, ni = f >> 1, t = f & 1;
        gBp[i] = W2b + (size_t)(bn*BN + ni*32 + l31) * KDIM + t*16 + half*8;
    }
    // prologue: stage buffer 0 (k0 = 0)
    #pragma unroll
    for (int i = 0; i < 2; i++) {
        gload_lds16(gBp[i], &Bs[0][(wave*2 + i) * 512]);
        gBp[i] += 32;
    }

    __syncthreads();   // evs/W1s/b1h written, Bs[0] staged+drained

    // GEMM1 B-operands: half0 = ev rows; half1 = unit vector at k=8 (bias path)
    bf16x8 evB0, evB1;
    if (half == 0) {
        evB0 = *(bf16x8*)&evs[(wave * 64 +      l31) * 8];
        evB1 = *(bf16x8*)&evs[(wave * 64 + 32 + l31) * 8];
    } else {
        evB0 = (bf16x8){};
        evB0[0] = (__bf16)1.0f;
        evB1 = evB0;
    }
    const f32x16 z16 = {};   // loop-invariant zero C-in for GEMM1

    f32x16 acc[8] = {};   // [rg*4 + ni]

    // GEMM1 chunk -> two row-groups' A-fragment pairs
#define COMPUTE_AF(K0, A00, A01, A10, A11) do {                               \
        bf16x8 w1f;                                                           \
        if (half == 0) {                                                      \
            w1f = *(const bf16x8*)&W1s[((K0) + l31) * 8];                     \
        } else {                                                              \
            w1f = (bf16x8){};                                                 \
            w1f[0] = *(const __bf16*)&b1h[(K0) + l31];                        \
        }                                                                     \
        f32x16 h0 = __builtin_amdgcn_mfma_f32_32x32x16_bf16(w1f, evB0, z16, 0, 0, 0); \
        h_to_af(h0, lane, half, A00, A01);                                    \
        f32x16 h1 = __builtin_amdgcn_mfma_f32_32x32x16_bf16(w1f, evB1, z16, 0, 0, 0); \
        h_to_af(h1, lane, half, A10, A11);                                    \
    } while (0)

#define GEMM2_STEP(CB, A00, A01, A10, A11) do {                               \
        __builtin_amdgcn_s_setprio(1);                                        \
        _Pragma("unroll")                                                     \
        for (int ni = 0; ni < 4; ni++) {                                      \
            bf16x8 bf0 = *(bf16x8*)&Bs[CB][(ni*2 + 0) * 512 + lane * 8];      \
            acc[ni]     = __builtin_amdgcn_mfma_f32_32x32x16_bf16(A00, bf0, acc[ni],     0, 0, 0); \
            acc[4 + ni] = __builtin_amdgcn_mfma_f32_32x32x16_bf16(A10, bf0, acc[4 + ni], 0, 0, 0); \
            bf16x8 bf1 = *(bf16x8*)&Bs[CB][(ni*2 + 1) * 512 + lane * 8];      \
            acc[ni]     = __builtin_amdgcn_mfma_f32_32x32x16_bf16(A01, bf1, acc[ni],     0, 0, 0); \
            acc[4 + ni] = __builtin_amdgcn_mfma_f32_32x32x16_bf16(A11, bf1, acc[4 + ni], 0, 0, 0); \
        }                                                                     \
        __builtin_amdgcn_s_setprio(0);                                        \
    } while (0)

    bf16x8 aA00, aA01, aA10, aA11;   // af set for even iters
    bf16x8 aB00, aB01, aB10, aB11;   // af set for odd iters
    COMPUTE_AF(0, aA00, aA01, aA10, aA11);

    for (int it = 0; it < NITER; it += 2) {
        // ---- even half: compute on Bs[0]/afA, prepare it+1 ----
        #pragma unroll
        for (int i = 0; i < 2; i++) {               // stage tile it+1 -> Bs[1]
            gload_lds16(gBp[i], &Bs[1][(wave*2 + i) * 512]);
            gBp[i] += 32;
        }
        COMPUTE_AF((it + 1) * 32, aB00, aB01, aB10, aB11);
        GEMM2_STEP(0, aA00, aA01, aA10, aA11);
        __syncthreads();                             // drains stage(it+1)

        // ---- odd half: compute on Bs[1]/afB, prepare it+2 ----
        if (it + 2 < NITER) {
            #pragma unroll
            for (int i = 0; i < 2; i++) {           // stage tile it+2 -> Bs[0]
                gload_lds16(gBp[i], &Bs[0][(wave*2 + i) * 512]);
                gBp[i] += 32;
            }
            COMPUTE_AF((it + 2) * 32, aA00, aA01, aA10, aA11);
        }
        GEMM2_STEP(1, aB00, aB01, aB10, aB11);
        __syncthreads();                             // drains stage(it+2)
    }
#undef COMPUTE_AF
#undef GEMM2_STEP

    // epilogue: 32x32 C/D layout: col = lane&31, row = (r&3)+8*(r>>2)+4*half
    #pragma unroll
    for (int rg = 0; rg < 2; rg++) {
        int rbase = bm*BM + wave*64 + rg*32 + 4*half;
        #pragma unroll
        for (int ni = 0; ni < 4; ni++) {
            int col = bn*BN + ni*32 + l31;
            float bias = b2[col];
            #pragma unroll
            for (int r = 0; r < 16; r++) {
                int row = rbase + (r & 3) + 8 * (r >> 2);
                C[(size_t)row * EMB + col] = acc[rg*4 + ni][r] + bias;
            }
        }
    }
}

extern "C" void kernel_launch(void* const* d_in, const int* in_sizes, int n_in,
                              void* d_out, int out_size, void* d_ws, size_t ws_size,
                              hipStream_t stream) {
    const float* x      = (const float*)d_in[0];  // [16,2048,8]
    const float* params = (const float*)d_in[1];  // [8,3]
    const float* W1     = (const float*)d_in[2];  // [2048,8]
    const float* b1     = (const float*)d_in[3];  // [2048]
    const float* W2     = (const float*)d_in[4];  // [512,2048]
    const float* b2     = (const float*)d_in[5];  // [512]
    float* out = (float*)d_out;                   // [32768,512]

    char* ws = (char*)d_ws;
    __hip_bfloat16* W2b  = (__hip_bfloat16*)ws;              // 2 MB
    __hip_bfloat16* W1bg = (__hip_bfloat16*)(ws + 2097152);  // 32 KB

    k_prep<<<1040, 256, 0, stream>>>(W2, W1, W2b, W1bg);
    k_gemm<<<(NS/BM) * (EMB/BN), 256, 0, stream>>>(x, params, W1bg, b1, W2b, b2, out);
}

// Round 5
// 150.628 us; speedup vs baseline: 1.1776x; 1.0024x over previous
//
#include <hip/hip_runtime.h>
#include <hip/hip_bf16.h>

#define NS 32768          // B*S samples
#define EMB 512
#define KDIM 2048
#define BM 256
#define BN 128
#define NITER (KDIM / 32)

typedef float f32x16 __attribute__((ext_vector_type(16)));
typedef __bf16 bf16x8 __attribute__((ext_vector_type(8)));
typedef __bf16 bf16x2 __attribute__((ext_vector_type(2)));
typedef unsigned int u32;
typedef const __attribute__((address_space(1))) u32* gptr_t;
typedef __attribute__((address_space(3))) u32* lptr_t;

__device__ __forceinline__ void gload_lds16(const void* g, void* l) {
    __builtin_amdgcn_global_load_lds((gptr_t)g, (lptr_t)l, 16, 0, 0);
}

// pack two relu'd floats into one u32 of 2 bf16 (v_cvt_pk_bf16_f32)
__device__ __forceinline__ u32 pkrelu(float lo, float hi) {
    union { bf16x2 h; u32 u; } c;
    c.h[0] = (__bf16)fmaxf(lo, 0.f);
    c.h[1] = (__bf16)fmaxf(hi, 0.f);
    return c.u;
}

__device__ __forceinline__ bf16x8 mk_af(u32 a, u32 b, u32 c, u32 d) {
    union { u32 u[4]; bf16x8 v; } t;
    t.u[0] = a; t.u[1] = b; t.u[2] = c; t.u[3] = d;
    return t.v;
}

// GEMM1 C/D regs -> two GEMM2 A-fragments. With the hidden-index
// pre-permutation (W1/b1 rows permuted by p(i) at stage time), D reg r at
// (l31,half) holds H_orig[k0 + t*16 + half*8 + j] exactly in A-frag order:
// af0 = regs 0..7 pairwise-packed, af1 = regs 8..15. No cross-lane ops.
__device__ __forceinline__ void h_to_af(const f32x16 h, bf16x8& af0, bf16x8& af1) {
    af0 = mk_af(pkrelu(h[0], h[1]),  pkrelu(h[2], h[3]),
                pkrelu(h[4], h[5]),  pkrelu(h[6], h[7]));
    af1 = mk_af(pkrelu(h[8], h[9]),  pkrelu(h[10], h[11]),
                pkrelu(h[12], h[13]), pkrelu(h[14], h[15]));
}

// ---- prep: W2 -> bf16 (1024 blocks); W1 -> bf16 (16 blocks) ----
__global__ __launch_bounds__(256) void k_prep(const float* __restrict__ W2,
                                              const float* __restrict__ W1,
                                              __hip_bfloat16* __restrict__ W2b,
                                              __hip_bfloat16* __restrict__ W1bg) {
    int t = threadIdx.x;
    if (blockIdx.x < 1024) {
        int i = (blockIdx.x * 256 + t) * 4;
        float4 v = *(const float4*)(W2 + i);
        __hip_bfloat16 o[4];
        o[0] = __float2bfloat16(v.x); o[1] = __float2bfloat16(v.y);
        o[2] = __float2bfloat16(v.z); o[3] = __float2bfloat16(v.w);
        *(ulong1*)(W2b + i) = *(ulong1*)o;
    } else {
        int j = (blockIdx.x - 1024) * 1024 + t * 4;   // 16 blocks x 1024
        float4 w = *(const float4*)(W1 + j);
        __hip_bfloat16 p[4];
        p[0] = __float2bfloat16(w.x); p[1] = __float2bfloat16(w.y);
        p[2] = __float2bfloat16(w.z); p[3] = __float2bfloat16(w.w);
        *(ulong1*)(W1bg + j) = *(ulong1*)p;
    }
}

// ---- fused: C[256,128-tile] = relu(ev @ W1^T + b1) @ W2b^T + b2 ----
// vs round 4:
//  * 512-thread blocks (8 waves), each wave owns ONE 32-row group:
//    2 blocks/CU -> 4 waves/SIMD (was 2) for latency hiding.
//  * hidden-index pre-permutation p(i) (quad swap 1<->2, 5<->6 per 32-chunk)
//    applied to W1s/b1h staging: GEMM1 D regs land directly in GEMM2 A-frag
//    order -> permlane32_swap eliminated entirely. W2 ordering unchanged.
//  * b1 folded into GEMM1 MFMA k=8 slot (round 4, verified).
//  * GEMM1+pack pipelined one iter ahead; setprio(1) around MFMA2 cluster.
__global__ __launch_bounds__(512, 4) void k_gemm(
        const float* __restrict__ x,       // [NS, 8]
        const float* __restrict__ params,  // [8, 3]
        const __hip_bfloat16* __restrict__ W1bg,  // [2048, 8] bf16
        const float* __restrict__ b1,      // [2048]
        const __hip_bfloat16* __restrict__ W2b,   // [512, 2048] bf16
        const float* __restrict__ b2,      // [512]
        float* __restrict__ C) {           // [NS, 512]
    __shared__ __hip_bfloat16 Bs[2][8 * 512];  // double-buffered, 2 x 8 KB
    __shared__ __hip_bfloat16 W1s[KDIM * 8];   // 32 KB (rows permuted by p)
    __shared__ __hip_bfloat16 b1h[KDIM];       // 4 KB  (permuted by p)
    __shared__ __hip_bfloat16 evs[BM * 8];     // 4 KB  -> total 56 KB, 2 blk/CU

    int tid = threadIdx.x, wave = tid >> 6, lane = tid & 63;
    int l31 = lane & 31, half = lane >> 5;
    int bx = blockIdx.x, bm = bx >> 2, bn = bx & 3;

    // --- inline ev for this block's 256 rows (threads 0..255, 1 sample each)
    if (tid < 256) {
        float K1[8], K2[8];
        #pragma unroll
        for (int i = 0; i < 8; i++) {
            float a = params[i*3+0], b = params[i*3+1], g = params[i*3+2];
            float sa, ca, sb, cb, sg, cg;
            __sincosf(a, &sa, &ca);
            __sincosf(b, &sb, &cb);
            __sincosf(g, &sg, &cg);
            K1[i] = sa*sb*sg + ca*cg;
            K2[i] = cb*sg;
        }
        int n = bm * BM + tid;
        float4 x0 = *(const float4*)(x + (size_t)n*8);
        float4 x1 = *(const float4*)(x + (size_t)n*8 + 4);
        float xs[8] = {x0.x, x0.y, x0.z, x0.w, x1.x, x1.y, x1.z, x1.w};
        float z[8];
        #pragma unroll
        for (int i = 0; i < 8; i++) {
            float s, c;
            __sincosf(xs[i], &s, &c);
            z[i] = c * K1[i] - s * K2[i];
        }
        float evv[8];
        float p = z[0];
        #pragma unroll
        for (int j = 1; j < 8; j++) { p *= z[j]; evv[j] = p; }
        float sfx = z[7];
        #pragma unroll
        for (int j = 6; j >= 1; j--) sfx *= z[j];
        evv[0] = sfx;
        __hip_bfloat16 o[8];
        #pragma unroll
        for (int i = 0; i < 8; i++) o[i] = __float2bfloat16(evv[i]);
        *(bf16x8*)&evs[tid * 8] = *(bf16x8*)o;
    }
    // --- stage W1 (bf16) + b1 (bf16) into LDS, rows permuted by p(i):
    //     within each 32-chunk, swap quads 1<->2 and 5<->6.
    for (int i = tid; i < KDIM; i += 512) {
        int q = (i >> 2) & 3;
        int src = i + ((q == 1) ? 4 : (q == 2) ? -4 : 0);
        *(bf16x8*)&W1s[i * 8] = *(const bf16x8*)(W1bg + (size_t)src * 8);
        b1h[i] = __float2bfloat16(b1[src]);
    }

    // B staging: wave stages frag f = wave (8 frags = 4 ni x 2 t; f = ni*2+t)
    const __hip_bfloat16* gBp =
        W2b + (size_t)(bn*BN + (wave >> 1)*32 + l31) * KDIM + (wave & 1)*16 + half*8;
    // prologue: stage buffer 0 (k0 = 0)
    gload_lds16(gBp, &Bs[0][wave * 512]);
    gBp += 32;

    __syncthreads();   // evs/W1s/b1h written, Bs[0] staged+drained

    // GEMM1 B-operand: half0 = this wave's 32 ev rows; half1 = unit at k=8
    bf16x8 evB;
    if (half == 0) {
        evB = *(bf16x8*)&evs[(wave * 32 + l31) * 8];
    } else {
        evB = (bf16x8){};
        evB[0] = (__bf16)1.0f;
    }
    const f32x16 z16 = {};   // loop-invariant zero C-in for GEMM1

    f32x16 acc[4] = {};   // [ni]

#define COMPUTE_AF(K0, A0, A1) do {                                           \
        bf16x8 w1f;                                                           \
        if (half == 0) {                                                      \
            w1f = *(const bf16x8*)&W1s[((K0) + l31) * 8];                     \
        } else {                                                              \
            w1f = (bf16x8){};                                                 \
            w1f[0] = *(const __bf16*)&b1h[(K0) + l31];                        \
        }                                                                     \
        f32x16 h = __builtin_amdgcn_mfma_f32_32x32x16_bf16(w1f, evB, z16, 0, 0, 0); \
        h_to_af(h, A0, A1);                                                   \
    } while (0)

#define GEMM2_STEP(CB, A0, A1) do {                                           \
        __builtin_amdgcn_s_setprio(1);                                        \
        _Pragma("unroll")                                                     \
        for (int ni = 0; ni < 4; ni++) {                                      \
            bf16x8 bf0 = *(bf16x8*)&Bs[CB][(ni*2 + 0) * 512 + lane * 8];      \
            acc[ni] = __builtin_amdgcn_mfma_f32_32x32x16_bf16(A0, bf0, acc[ni], 0, 0, 0); \
            bf16x8 bf1 = *(bf16x8*)&Bs[CB][(ni*2 + 1) * 512 + lane * 8];      \
            acc[ni] = __builtin_amdgcn_mfma_f32_32x32x16_bf16(A1, bf1, acc[ni], 0, 0, 0); \
        }                                                                     \
        __builtin_amdgcn_s_setprio(0);                                        \
    } while (0)

    bf16x8 aA0, aA1;   // af set for even iters
    bf16x8 aB0, aB1;   // af set for odd iters
    COMPUTE_AF(0, aA0, aA1);

    for (int it = 0; it < NITER; it += 2) {
        // ---- even half: compute on Bs[0]/afA, prepare it+1 ----
        gload_lds16(gBp, &Bs[1][wave * 512]);   // stage tile it+1 -> Bs[1]
        gBp += 32;
        COMPUTE_AF((it + 1) * 32, aB0, aB1);
        GEMM2_STEP(0, aA0, aA1);
        __syncthreads();                         // drains stage(it+1)

        // ---- odd half: compute on Bs[1]/afB, prepare it+2 ----
        if (it + 2 < NITER) {
            gload_lds16(gBp, &Bs[0][wave * 512]); // stage tile it+2 -> Bs[0]
            gBp += 32;
            COMPUTE_AF((it + 2) * 32, aA0, aA1);
        }
        GEMM2_STEP(1, aB0, aB1);
        __syncthreads();                         // drains stage(it+2)
    }
#undef COMPUTE_AF
#undef GEMM2_STEP

    // epilogue: 32x32 C/D layout: col = lane&31, row = (r&3)+8*(r>>2)+4*half
    int rbase = bm*BM + wave*32 + 4*half;
    #pragma unroll
    for (int ni = 0; ni < 4; ni++) {
        int col = bn*BN + ni*32 + l31;
        float bias = b2[col];
        #pragma unroll
        for (int r = 0; r < 16; r++) {
            int row = rbase + (r & 3) + 8 * (r >> 2);
            C[(size_t)row * EMB + col] = acc[ni][r] + bias;
        }
    }
}

extern "C" void kernel_launch(void* const* d_in, const int* in_sizes, int n_in,
                              void* d_out, int out_size, void* d_ws, size_t ws_size,
                              hipStream_t stream) {
    const float* x      = (const float*)d_in[0];  // [16,2048,8]
    const float* params = (const float*)d_in[1];  // [8,3]
    const float* W1     = (const float*)d_in[2];  // [2048,8]
    const float* b1     = (const float*)d_in[3];  // [2048]
    const float* W2     = (const float*)d_in[4];  // [512,2048]
    const float* b2     = (const float*)d_in[5];  // [512]
    float* out = (float*)d_out;                   // [32768,512]

    char* ws = (char*)d_ws;
    __hip_bfloat16* W2b  = (__hip_bfloat16*)ws;              // 2 MB
    __hip_bfloat16* W1bg = (__hip_bfloat16*)(ws + 2097152);  // 32 KB

    k_prep<<<1040, 256, 0, stream>>>(W2, W1, W2b, W1bg);
    k_gemm<<<(NS/BM) * (EMB/BN), 512, 0, stream>>>(x, params, W1bg, b1, W2b, b2, out);
}